// Round 8
// baseline (10048.936 us; speedup 1.0000x reference)
//
#include <hip/hip_runtime.h>
#include <hip/hip_bf16.h>

#define BN_EPS 1e-5f
#define SLICE_SHIFT 13
#define SLICE 8192

typedef unsigned short ushort_t;
typedef unsigned int u32x4 __attribute__((ext_vector_type(4)));

__device__ inline unsigned ntl_u32(const unsigned* p) { return __builtin_nontemporal_load(p); }

__device__ inline ushort_t f2bf(float x) {
  unsigned u = __float_as_uint(x);
  unsigned r = (u + 0x7FFFu + ((u >> 16) & 1u)) >> 16;
  return (ushort_t)r;
}
__device__ inline void bf2x(unsigned u, float& a, float& b) {
  a = __uint_as_float(u << 16);
  b = __uint_as_float(u & 0xFFFF0000u);
}

// ---------------- xcatp = concat(xs, xt) as bf16, rows padded to 32 (64B) ----------------
__global__ __launch_bounds__(256) void k_xcat(
    const float* __restrict__ xs, const float* __restrict__ xt,
    ushort_t* __restrict__ xcatp, int N) {
  long i = (long)blockIdx.x * 256 + threadIdx.x;
  if (i >= (long)N * 32) return;
  int n = (int)(i >> 5), f = (int)(i & 31);
  float v = 0.f;
  if (f < 6) v = xs[(long)n * 6 + f];
  else if (f < 20) v = xt[(long)n * 14 + f - 6];
  xcatp[i] = f2bf(v);
}

// ============ src-mega-bucket scatter: 13 buckets of 8192 src nodes ============
// entry = (src_local<<17) | dst   (src_local<8192: 13b, dst<131072: 17b)
__global__ __launch_bounds__(256) void k_sc(
    const int* __restrict__ srcA, const int* __restrict__ dstA,
    unsigned* __restrict__ gcur, unsigned* __restrict__ bbuf,
    int E, unsigned CAPS) {
  __shared__ unsigned cnt[16], base[16];
  int tid = threadIdx.x;
  for (long e0 = (long)blockIdx.x * 256; e0 < E; e0 += (long)gridDim.x * 256) {
    long e = e0 + tid;
    if (tid < 16) cnt[tid] = 0;
    __syncthreads();
    int s = 0, d = 0; unsigned bk = 0, rank = 0;
    bool valid = (e < E);
    if (valid) {
      s = srcA[e]; d = dstA[e];
      bk = (unsigned)(s >> SLICE_SHIFT);
      rank = atomicAdd(&cnt[bk], 1u);
    }
    __syncthreads();
    if (tid < 16) { unsigned c = cnt[tid]; if (c) base[tid] = atomicAdd(&gcur[tid * 16], c); }
    __syncthreads();
    if (valid) {
      unsigned pos = base[bk] + rank;
      if (pos < CAPS)
        bbuf[(size_t)bk * CAPS + pos] = ((unsigned)(s & (SLICE - 1)) << 17) | (unsigned)d;
    }
    __syncthreads();
  }
}

// ============ layer-1 atomic aggregation: agg1[dst*21 + 0..19] += x[src], +20 = deg ============
__global__ __launch_bounds__(256) void k_a1(
    const unsigned* __restrict__ gcur, const unsigned* __restrict__ bbuf,
    const ushort_t* __restrict__ xcatp, float* __restrict__ agg1,
    int NSL, unsigned CAPS) {
  long gtid = (long)blockIdx.x * 256 + threadIdx.x;
  long gstr = (long)gridDim.x * 256;
  for (int bk = 0; bk < NSL; ++bk) {
    unsigned cnt = gcur[bk * 16]; if (cnt > CAPS) cnt = CAPS;
    const unsigned* bb = bbuf + (size_t)bk * CAPS;
    int sbase = bk << SLICE_SHIFT;
    for (long i = gtid; i < cnt; i += gstr) {
      unsigned e = ntl_u32(bb + i);
      int dst = (int)(e & 0x1FFFFu);
      int src = sbase + (int)(e >> 17);
      const u32x4* xr = (const u32x4*)(xcatp + (size_t)src * 32);  // L2-resident slice
      u32x4 A = xr[0], B = xr[1], C = xr[2];
      float* ag = agg1 + (long)dst * 21;
      float u, v;
      bf2x(A.x, u, v); atomicAdd(ag + 0, u);  atomicAdd(ag + 1, v);
      bf2x(A.y, u, v); atomicAdd(ag + 2, u);  atomicAdd(ag + 3, v);
      bf2x(A.z, u, v); atomicAdd(ag + 4, u);  atomicAdd(ag + 5, v);
      bf2x(A.w, u, v); atomicAdd(ag + 6, u);  atomicAdd(ag + 7, v);
      bf2x(B.x, u, v); atomicAdd(ag + 8, u);  atomicAdd(ag + 9, v);
      bf2x(B.y, u, v); atomicAdd(ag + 10, u); atomicAdd(ag + 11, v);
      bf2x(B.z, u, v); atomicAdd(ag + 12, u); atomicAdd(ag + 13, v);
      bf2x(B.w, u, v); atomicAdd(ag + 14, u); atomicAdd(ag + 15, v);
      bf2x(C.x, u, v); atomicAdd(ag + 16, u); atomicAdd(ag + 17, v);
      bf2x(C.y, u, v); atomicAdd(ag + 18, u); atomicAdd(ag + 19, v);
      atomicAdd(ag + 20, 1.0f);
    }
  }
}

// ============ SAGE1: h1 = (agg1/deg)@W1l + b1l + x@W1r, + BN1 stats + rdeg ============
__global__ __launch_bounds__(256) void k_sage1(
    const float* __restrict__ agg1,
    const float* __restrict__ xs, const float* __restrict__ xt,
    const float* __restrict__ W1l, const float* __restrict__ b1l,
    const float* __restrict__ W1r,
    float* __restrict__ h1, float* __restrict__ rdeg_g,
    float* __restrict__ sum1, float* __restrict__ sq1, int N) {
  __shared__ float sWl[1280], sWr[1280];
  __shared__ float sm[4][21], sx[4][20];
  __shared__ float ls[256], lq[256];
  int tid = threadIdx.x;
  for (int i = tid; i < 1280; i += 256) { sWl[i] = W1l[i]; sWr[i] = W1r[i]; }
  int ln = tid >> 6, c = tid & 63;
  int n = blockIdx.x * 4 + ln;
  if (n < N && c < 21) sm[ln][c] = agg1[(long)n * 21 + c];
  if (n < N && c < 20) sx[ln][c] = (c < 6) ? xs[(long)n * 6 + c] : xt[(long)n * 14 + c - 6];
  __syncthreads();
  float s_acc = 0.f, q_acc = 0.f;
  if (n < N) {
    float rd = 1.f / fmaxf(sm[ln][20], 1.f);
    if (c == 0) rdeg_g[n] = rd;
    float acc = b1l[c];
#pragma unroll
    for (int f = 0; f < 20; ++f)
      acc += (sm[ln][f] * rd) * sWl[f * 64 + c] + sx[ln][f] * sWr[f * 64 + c];
    h1[(long)n * 64 + c] = acc;
    s_acc = acc; q_acc = acc * acc;
  }
  ls[tid] = s_acc; lq[tid] = q_acc;
  __syncthreads();
  if (tid < 64) {
    float s = ls[tid], q = lq[tid];
#pragma unroll
    for (int r = 1; r < 4; ++r) { s += ls[tid + 64 * r]; q += lq[tid + 64 * r]; }
    atomicAdd(&sum1[tid], s);
    atomicAdd(&sq1[tid], q);
  }
}

// -------- BN1 + ReLU + p2l = h@W2l (bf16), p2r = h@W2r (in-place into h1) -------
__global__ __launch_bounds__(256) void k_bn1_proj(
    float* __restrict__ h1,
    const float* __restrict__ sum, const float* __restrict__ sq,
    const float* __restrict__ g, const float* __restrict__ be,
    const float* __restrict__ W2l, const float* __restrict__ W2r,
    ushort_t* __restrict__ p2l, int N) {
  __shared__ float sWl[64 * 32], sWr[64 * 32];
  __shared__ float sh[8][64];
  __shared__ float sscale[64], sshift[64];
  int tid = threadIdx.x;
  for (int i = tid; i < 2048; i += 256) { sWl[i] = W2l[i]; sWr[i] = W2r[i]; }
  if (tid < 64) {
    float m = sum[tid] / (float)N;
    float v = sq[tid] / (float)N - m * m;
    float inv = rsqrtf(v + BN_EPS);
    float sc = g[tid] * inv;
    sscale[tid] = sc;
    sshift[tid] = be[tid] - m * sc;
  }
  __syncthreads();
  long base = (long)blockIdx.x * 512;
#pragma unroll
  for (int k = 0; k < 2; ++k) {
    long j = base + tid + k * 256;
    if (j < (long)N * 64) {
      int c = (int)(j & 63);
      float v = h1[j] * sscale[c] + sshift[c];
      sh[(tid + k * 256) >> 6][c] = fmaxf(v, 0.f);
    }
  }
  __syncthreads();
  int c2 = tid & 31, ln = tid >> 5;
  int n = blockIdx.x * 8 + ln;
  if (n < N) {
    float al = 0.f, ar = 0.f;
#pragma unroll
    for (int c = 0; c < 64; ++c) {
      float hv = sh[ln][c];
      al += hv * sWl[c * 32 + c2];
      ar += hv * sWr[c * 32 + c2];
    }
    p2l[(long)n * 32 + c2] = f2bf(al);
    h1[(long)n * 64 + c2] = ar;   // p2r in-place
  }
}

// ============ layer-2 atomic aggregation: agg2[dst*32 + 0..31] += p2l[src] ============
__global__ __launch_bounds__(256) void k_a2(
    const unsigned* __restrict__ gcur, const unsigned* __restrict__ bbuf,
    const ushort_t* __restrict__ p2l, float* __restrict__ agg2,
    int NSL, unsigned CAPS) {
  long gtid = (long)blockIdx.x * 256 + threadIdx.x;
  long gstr = (long)gridDim.x * 256;
  for (int bk = 0; bk < NSL; ++bk) {
    unsigned cnt = gcur[bk * 16]; if (cnt > CAPS) cnt = CAPS;
    const unsigned* bb = bbuf + (size_t)bk * CAPS;
    int sbase = bk << SLICE_SHIFT;
    for (long i = gtid; i < cnt; i += gstr) {
      unsigned e = ntl_u32(bb + i);
      int dst = (int)(e & 0x1FFFFu);
      int src = sbase + (int)(e >> 17);
      const u32x4* pr = (const u32x4*)(p2l + (size_t)src * 32);  // 64B row, L2-resident slice
      u32x4 A = pr[0], B = pr[1], C = pr[2], D = pr[3];
      float* ag = agg2 + (long)dst * 32;
      float u, v;
      bf2x(A.x, u, v); atomicAdd(ag + 0, u);  atomicAdd(ag + 1, v);
      bf2x(A.y, u, v); atomicAdd(ag + 2, u);  atomicAdd(ag + 3, v);
      bf2x(A.z, u, v); atomicAdd(ag + 4, u);  atomicAdd(ag + 5, v);
      bf2x(A.w, u, v); atomicAdd(ag + 6, u);  atomicAdd(ag + 7, v);
      bf2x(B.x, u, v); atomicAdd(ag + 8, u);  atomicAdd(ag + 9, v);
      bf2x(B.y, u, v); atomicAdd(ag + 10, u); atomicAdd(ag + 11, v);
      bf2x(B.z, u, v); atomicAdd(ag + 12, u); atomicAdd(ag + 13, v);
      bf2x(B.w, u, v); atomicAdd(ag + 14, u); atomicAdd(ag + 15, v);
      bf2x(C.x, u, v); atomicAdd(ag + 16, u); atomicAdd(ag + 17, v);
      bf2x(C.y, u, v); atomicAdd(ag + 18, u); atomicAdd(ag + 19, v);
      bf2x(C.z, u, v); atomicAdd(ag + 20, u); atomicAdd(ag + 21, v);
      bf2x(C.w, u, v); atomicAdd(ag + 22, u); atomicAdd(ag + 23, v);
      bf2x(D.x, u, v); atomicAdd(ag + 24, u); atomicAdd(ag + 25, v);
      bf2x(D.y, u, v); atomicAdd(ag + 26, u); atomicAdd(ag + 27, v);
      bf2x(D.z, u, v); atomicAdd(ag + 28, u); atomicAdd(ag + 29, v);
      bf2x(D.w, u, v); atomicAdd(ag + 30, u); atomicAdd(ag + 31, v);
    }
  }
}

// ============ h2 = agg2*rdeg + b2l + p2r (in h1), + BN2 stats ============
__global__ __launch_bounds__(256) void k_h2s(
    const float* __restrict__ agg2, const float* __restrict__ b2l,
    const float* __restrict__ rdeg_g,
    float* __restrict__ h1,
    float* __restrict__ sum2, float* __restrict__ sq2, int N) {
  __shared__ float ls[256], lq[256];
  int tid = threadIdx.x;
  int c = tid & 31, ln = tid >> 5;
  int n = blockIdx.x * 8 + ln;
  float s_acc = 0.f, q_acc = 0.f;
  if (n < N) {
    long idx = (long)n * 64 + c;
    float h2 = agg2[(long)n * 32 + c] * rdeg_g[n] + b2l[c] + h1[idx];
    h1[idx] = h2;
    s_acc = h2; q_acc = h2 * h2;
  }
  ls[tid] = s_acc; lq[tid] = q_acc;
  __syncthreads();
  if (tid < 32) {
    float s = ls[tid], q = lq[tid];
#pragma unroll
    for (int r = 1; r < 8; ++r) { s += ls[tid + 32 * r]; q += lq[tid + 32 * r]; }
    atomicAdd(&sum2[tid], s);
    atomicAdd(&sq2[tid], q);
  }
}

// ---------------- BN2 + ReLU + channel-mean + MLP head ----------------------
__global__ __launch_bounds__(256) void k_final(
    const float* __restrict__ h2,    // at [n*64+c], c<32
    const float* __restrict__ sum, const float* __restrict__ sq,
    const float* __restrict__ g, const float* __restrict__ be,
    const float* __restrict__ Wp, const float* __restrict__ bp,
    const float* __restrict__ Wo, const float* __restrict__ bo,
    float* __restrict__ out, int N) {
  int tid = threadIdx.x;
  int c = tid & 31, ln = tid >> 5;
  int n = blockIdx.x * 8 + ln;
  if (n >= N) return;
  float m = sum[c] / (float)N;
  float v = sq[c] / (float)N - m * m;
  float inv = rsqrtf(v + BN_EPS);
  float sc = g[c] * inv;
  float sh = be[c] - m * sc;
  float x = fmaxf(h2[(long)n * 64 + c] * sc + sh, 0.f);
#pragma unroll
  for (int msk = 16; msk >= 1; msk >>= 1) x += __shfl_xor(x, msk);
  float lr = x * (1.0f / 32.0f);
  float e = fmaxf(lr * Wp[c] + bp[c], 0.f) * Wo[c];
#pragma unroll
  for (int msk = 16; msk >= 1; msk >>= 1) e += __shfl_xor(e, msk);
  if (c == 0) out[n] = e + bo[0];
}

// ===================== fallback (round-0) atomic path =====================
__global__ __launch_bounds__(256) void k_edge_agg20(
    const int* __restrict__ srcA, const int* __restrict__ dstA,
    const float* __restrict__ xs, const float* __restrict__ xt,
    float* __restrict__ agg, float* __restrict__ deg, int E) {
  long gtid = (long)blockIdx.x * blockDim.x + threadIdx.x;
  int f = (int)(gtid & 31);
  long e = gtid >> 5;
  if (e >= E) return;
  int s = srcA[e], d = dstA[e];
  if (f < 20) {
    float v = (f < 6) ? xs[(long)s * 6 + f] : xt[(long)s * 14 + (f - 6)];
    atomicAdd(&agg[(long)d * 20 + f], v);
  }
  if (f == 0) atomicAdd(&deg[d], 1.0f);
}

__global__ __launch_bounds__(256) void k_sage1_fb(
    const float* __restrict__ agg, const float* __restrict__ deg,
    const float* __restrict__ xs, const float* __restrict__ xt,
    const float* __restrict__ W1l, const float* __restrict__ b1l,
    const float* __restrict__ W1r, float* __restrict__ h1, int N) {
  __shared__ float sWl[1280], sWr[1280];
  __shared__ float sm[4][20], sx[4][20];
  int tid = threadIdx.x;
  for (int i = tid; i < 1280; i += 256) { sWl[i] = W1l[i]; sWr[i] = W1r[i]; }
  int ln = tid >> 6, c = tid & 63;
  int n = blockIdx.x * 4 + ln;
  if (n < N && c < 20) {
    float dv = fmaxf(deg[n], 1.0f);
    sm[ln][c] = agg[(long)n * 20 + c] / dv;
    sx[ln][c] = (c < 6) ? xs[(long)n * 6 + c] : xt[(long)n * 14 + (c - 6)];
  }
  __syncthreads();
  if (n < N) {
    float acc = b1l[c];
#pragma unroll
    for (int f = 0; f < 20; ++f)
      acc += sm[ln][f] * sWl[f * 64 + c] + sx[ln][f] * sWr[f * 64 + c];
    h1[(long)n * 64 + c] = acc;
  }
}

__global__ __launch_bounds__(256) void k_stats(
    const float* __restrict__ h, int N, int C,
    float* __restrict__ sum, float* __restrict__ sq) {
  int tid = threadIdx.x;
  int rows = 256 / C;
  int c = tid % C, r = tid / C;
  float s = 0.f, q = 0.f;
  for (long n = (long)blockIdx.x * rows + r; n < N; n += (long)gridDim.x * rows) {
    float v = h[n * C + c];
    s += v; q += v * v;
  }
  __shared__ float ls[256], lq[256];
  ls[tid] = s; lq[tid] = q;
  __syncthreads();
  if (r == 0) {
    for (int rr = 1; rr < rows; ++rr) { s += ls[c + rr * C]; q += lq[c + rr * C]; }
    atomicAdd(&sum[c], s);
    atomicAdd(&sq[c], q);
  }
}

__global__ __launch_bounds__(256) void k_bn1_proj_fb(
    const float* __restrict__ h1,
    const float* __restrict__ sum, const float* __restrict__ sq,
    const float* __restrict__ g, const float* __restrict__ be,
    const float* __restrict__ W2l, const float* __restrict__ W2r,
    float* __restrict__ p2l, float* __restrict__ p2r, int N) {
  __shared__ float sWl[64 * 32], sWr[64 * 32];
  __shared__ float sh[8][64];
  __shared__ float sscale[64], sshift[64];
  int tid = threadIdx.x;
  for (int i = tid; i < 2048; i += 256) { sWl[i] = W2l[i]; sWr[i] = W2r[i]; }
  if (tid < 64) {
    float m = sum[tid] / (float)N;
    float v = sq[tid] / (float)N - m * m;
    float inv = rsqrtf(v + BN_EPS);
    float sc = g[tid] * inv;
    sscale[tid] = sc;
    sshift[tid] = be[tid] - m * sc;
  }
  __syncthreads();
  long base = (long)blockIdx.x * 512;
#pragma unroll
  for (int k = 0; k < 2; ++k) {
    long j = base + tid + k * 256;
    if (j < (long)N * 64) {
      int c = (int)(j & 63);
      float v = h1[j] * sscale[c] + sshift[c];
      sh[(tid + k * 256) >> 6][c] = fmaxf(v, 0.f);
    }
  }
  __syncthreads();
  int c2 = tid & 31, ln = tid >> 5;
  int n = blockIdx.x * 8 + ln;
  if (n < N) {
    float al = 0.f, ar = 0.f;
#pragma unroll
    for (int c = 0; c < 64; ++c) {
      float hv = sh[ln][c];
      al += hv * sWl[c * 32 + c2];
      ar += hv * sWr[c * 32 + c2];
    }
    p2l[(long)n * 32 + c2] = al;
    p2r[(long)n * 32 + c2] = ar;
  }
}

__global__ __launch_bounds__(256) void k_edge_agg32(
    const int* __restrict__ srcA, const int* __restrict__ dstA,
    const float* __restrict__ p, float* __restrict__ agg, int E) {
  long gtid = (long)blockIdx.x * blockDim.x + threadIdx.x;
  int f = (int)(gtid & 31);
  long e = gtid >> 5;
  if (e >= E) return;
  atomicAdd(&agg[(long)dstA[e] * 32 + f], p[(long)srcA[e] * 32 + f]);
}

__global__ __launch_bounds__(256) void k_h2_fb(
    const float* __restrict__ agg, const float* __restrict__ deg,
    const float* __restrict__ b2l, const float* __restrict__ p2r,
    float* __restrict__ h2, int N) {
  long i = (long)blockIdx.x * blockDim.x + threadIdx.x;
  if (i >= (long)N * 32) return;
  int n = (int)(i >> 5), f = (int)(i & 31);
  float dv = fmaxf(deg[n], 1.0f);
  h2[i] = agg[i] / dv + b2l[f] + p2r[i];
}

__global__ __launch_bounds__(256) void k_final_fb(
    const float* __restrict__ h2,
    const float* __restrict__ sum, const float* __restrict__ sq,
    const float* __restrict__ g, const float* __restrict__ be,
    const float* __restrict__ Wp, const float* __restrict__ bp,
    const float* __restrict__ Wo, const float* __restrict__ bo,
    float* __restrict__ out, int N) {
  int tid = threadIdx.x;
  int c = tid & 31, ln = tid >> 5;
  int n = blockIdx.x * 8 + ln;
  if (n >= N) return;
  float m = sum[c] / (float)N;
  float v = sq[c] / (float)N - m * m;
  float inv = rsqrtf(v + BN_EPS);
  float sc = g[c] * inv;
  float sh = be[c] - m * sc;
  float x = fmaxf(h2[(long)n * 32 + c] * sc + sh, 0.f);
#pragma unroll
  for (int msk = 16; msk >= 1; msk >>= 1) x += __shfl_xor(x, msk);
  float lr = x * (1.0f / 32.0f);
  float e = fmaxf(lr * Wp[c] + bp[c], 0.f) * Wo[c];
#pragma unroll
  for (int msk = 16; msk >= 1; msk >>= 1) e += __shfl_xor(e, msk);
  if (c == 0) out[n] = e + bo[0];
}

extern "C" void kernel_launch(void* const* d_in, const int* in_sizes, int n_in,
                              void* d_out, int out_size, void* d_ws, size_t ws_size,
                              hipStream_t stream) {
  const float* xs  = (const float*)d_in[0];
  const float* xt  = (const float*)d_in[1];
  const int*   ei  = (const int*)d_in[2];
  const float* W1l = (const float*)d_in[3];
  const float* b1l = (const float*)d_in[4];
  const float* W1r = (const float*)d_in[5];
  const float* g1  = (const float*)d_in[6];
  const float* be1 = (const float*)d_in[7];
  const float* W2l = (const float*)d_in[8];
  const float* b2l = (const float*)d_in[9];
  const float* W2r = (const float*)d_in[10];
  const float* g2  = (const float*)d_in[11];
  const float* be2 = (const float*)d_in[12];
  const float* Wp  = (const float*)d_in[13];
  const float* bp  = (const float*)d_in[14];
  const float* Wo  = (const float*)d_in[15];
  const float* bo  = (const float*)d_in[16];
  float* out = (float*)d_out;

  int N = in_sizes[0] / 6;
  int E = in_sizes[2] / 2;
  const int* srcA = ei;
  const int* dstA = ei + E;
  const int tb = 256;

  int NSL = (N + SLICE - 1) >> SLICE_SHIFT;
  // bucket capacity: mean edges/full-slice + ~6% + 1024 slack; round to 4
  unsigned CAPS = (unsigned)(((long)E << SLICE_SHIFT) / (N > 0 ? N : 1));
  CAPS += CAPS / 16 + 1024;
  CAPS = (CAPS + 3u) & ~3u;

  // ws layout (u32 units):
  // gcur[256] | stats[192] | aggA[37N] (agg1 21N; later agg2 32N overlays) |
  //   (xcatp bf16 occupies aggA+21N .. +37N)
  // bbuf[NSL*CAPS] | h1[64N] | p2l bf16[16N] | rdeg[N]
  size_t nu = (size_t)N;
  size_t off_gcur = 0;
  size_t off_stats = 256;
  size_t off_aggA = 448;
  size_t off_xcat = off_aggA + 21 * nu;         // N mult of 4 not guaranteed; pad:
  off_xcat = (off_xcat + 3) & ~(size_t)3;
  size_t off_bbuf = off_xcat + 16 * nu;
  off_bbuf = (off_bbuf + 3) & ~(size_t)3;
  size_t off_h1 = off_bbuf + (size_t)NSL * CAPS;
  off_h1 = (off_h1 + 3) & ~(size_t)3;
  size_t off_p2l = off_h1 + 64 * nu;
  size_t off_rdeg = off_p2l + 16 * nu;
  off_rdeg = (off_rdeg + 3) & ~(size_t)3;
  size_t needB = (off_rdeg + nu + ((37 * nu > off_bbuf - off_aggA) ? 8 : 0)) * 4;
  // ensure agg2 overlay (32N) fits inside [aggA, bbuf):
  bool overlay_ok = (off_bbuf - off_aggA) >= 32 * nu;

  if (ws_size >= needB && N <= 131072 && NSL <= 16 && overlay_ok) {
    unsigned* base32 = (unsigned*)d_ws;
    unsigned* gcur  = base32 + off_gcur;
    float*    stats = (float*)(base32 + off_stats);
    float* sum1 = stats, * sq1 = stats + 64, * sum2 = stats + 128, * sq2 = stats + 160;
    float*    agg1  = (float*)(base32 + off_aggA);
    float*    agg2  = agg1;                        // overlay after agg1 is dead
    ushort_t* xcatp = (ushort_t*)(base32 + off_xcat);
    unsigned* bbuf  = base32 + off_bbuf;
    float*    h1    = (float*)(base32 + off_h1);
    ushort_t* p2l   = (ushort_t*)(base32 + off_p2l);
    float*    rdeg  = (float*)(base32 + off_rdeg);

    // zero gcur + stats + agg1 (contiguous from 0 to off_aggA + 21N)
    hipMemsetAsync(base32, 0, (off_aggA + 21 * nu) * 4, stream);

    k_xcat<<<(int)(((long)N * 32 + tb - 1) / tb), tb, 0, stream>>>(xs, xt, xcatp, N);
    k_sc<<<1024, tb, 0, stream>>>(srcA, dstA, gcur, bbuf, E, CAPS);
    k_a1<<<1024, tb, 0, stream>>>(gcur, bbuf, xcatp, agg1, NSL, CAPS);
    k_sage1<<<(N + 3) / 4, tb, 0, stream>>>(agg1, xs, xt, W1l, b1l, W1r,
                                            h1, rdeg, sum1, sq1, N);
    // agg1 + xcatp now dead -> zero agg2 overlay region
    hipMemsetAsync(agg2, 0, 32 * nu * 4, stream);
    k_bn1_proj<<<(N + 7) / 8, tb, 0, stream>>>(h1, sum1, sq1, g1, be1, W2l, W2r, p2l, N);
    k_a2<<<1024, tb, 0, stream>>>(gcur, bbuf, p2l, agg2, NSL, CAPS);
    k_h2s<<<(N + 7) / 8, tb, 0, stream>>>(agg2, b2l, rdeg, h1, sum2, sq2, N);
    k_final<<<(N + 7) / 8, tb, 0, stream>>>(h1, sum2, sq2, g2, be2, Wp, bp, Wo, bo, out, N);
  } else {
    // ---- fallback: round-0 atomic path ----
    float* ws   = (float*)d_ws;
    float* deg  = ws;
    float* agg1 = deg + N;
    float* h1   = agg1 + (long)20 * N;
    float* agg2 = h1;
    float* h2   = h1 + (long)32 * N;
    float* p2l  = h1 + (long)64 * N;
    float* p2r  = p2l + (long)32 * N;
    float* stats = p2r + (long)32 * N;
    float* sum1 = stats, * sq1 = stats + 64, * sum2 = stats + 128, * sq2 = stats + 160;

    hipMemsetAsync(deg, 0, sizeof(float) * (size_t)(21 * (long)N), stream);
    hipMemsetAsync(stats, 0, sizeof(float) * 192, stream);

    long t1 = (long)E * 32;
    int eblocks = (int)((t1 + tb - 1) / tb);
    k_edge_agg20<<<eblocks, tb, 0, stream>>>(srcA, dstA, xs, xt, agg1, deg, E);
    k_sage1_fb<<<(N + 3) / 4, tb, 0, stream>>>(agg1, deg, xs, xt, W1l, b1l, W1r, h1, N);
    k_stats<<<1024, tb, 0, stream>>>(h1, N, 64, sum1, sq1);
    k_bn1_proj_fb<<<(N + 7) / 8, tb, 0, stream>>>(h1, sum1, sq1, g1, be1, W2l, W2r, p2l, p2r, N);
    hipMemsetAsync(agg2, 0, sizeof(float) * (size_t)(32 * (long)N), stream);
    k_edge_agg32<<<eblocks, tb, 0, stream>>>(srcA, dstA, p2l, agg2, E);
    k_h2_fb<<<(int)(((long)32 * N + tb - 1) / tb), tb, 0, stream>>>(agg2, deg, b2l, p2r, h2, N);
    k_stats<<<1024, tb, 0, stream>>>(h2, N, 32, sum2, sq2);
    k_final_fb<<<(N + 7) / 8, tb, 0, stream>>>(h2, sum2, sq2, g2, be2, Wp, bp, Wo, bo, out, N);
  }
}

// Round 9
// 1917.280 us; speedup vs baseline: 5.2412x; 5.2412x over previous
//
#include <hip/hip_runtime.h>
#include <hip/hip_bf16.h>
#include <hip/hip_fp16.h>

#define BN_EPS 1e-5f
#define SLICE_SHIFT 13
#define SLICE 8192

typedef unsigned int u32x4 __attribute__((ext_vector_type(4)));

__device__ inline unsigned ntl_u32(const unsigned* p) { return __builtin_nontemporal_load(p); }
__device__ inline void atomAddH2(__half2* p, __half2 v) { unsafeAtomicAdd(p, v); }

// ---------------- xcath = concat(xs, xt) as f16, rows padded to 32 (64B) ----------------
__global__ __launch_bounds__(256) void k_xcat(
    const float* __restrict__ xs, const float* __restrict__ xt,
    __half* __restrict__ xcath, int N) {
  long i = (long)blockIdx.x * 256 + threadIdx.x;
  if (i >= (long)N * 32) return;
  int n = (int)(i >> 5), f = (int)(i & 31);
  float v = 0.f;
  if (f < 6) v = xs[(long)n * 6 + f];
  else if (f < 20) v = xt[(long)n * 14 + f - 6];
  xcath[i] = __float2half(v);
}

// ============ src-mega-bucket scatter: slices of 8192 src nodes ============
// entry = (src_local<<17) | dst
__global__ __launch_bounds__(256) void k_sc(
    const int* __restrict__ srcA, const int* __restrict__ dstA,
    unsigned* __restrict__ gcur, unsigned* __restrict__ bbuf,
    int E, unsigned CAPS) {
  __shared__ unsigned cnt[16], base[16];
  int tid = threadIdx.x;
  for (long e0 = (long)blockIdx.x * 256; e0 < E; e0 += (long)gridDim.x * 256) {
    long e = e0 + tid;
    if (tid < 16) cnt[tid] = 0;
    __syncthreads();
    int s = 0, d = 0; unsigned bk = 0, rank = 0;
    bool valid = (e < E);
    if (valid) {
      s = srcA[e]; d = dstA[e];
      bk = (unsigned)(s >> SLICE_SHIFT);
      rank = atomicAdd(&cnt[bk], 1u);
    }
    __syncthreads();
    if (tid < 16) { unsigned c = cnt[tid]; if (c) base[tid] = atomicAdd(&gcur[tid * 16], c); }
    __syncthreads();
    if (valid) {
      unsigned pos = base[bk] + rank;
      if (pos < CAPS)
        bbuf[(size_t)bk * CAPS + pos] = ((unsigned)(s & (SLICE - 1)) << 17) | (unsigned)d;
    }
    __syncthreads();
  }
}

// ============ layer-1 agg: 32-lane group per edge, pk f16 atomics ============
// agg1h row: 32 f16 (feat 0..19, deg at 20)
__global__ __launch_bounds__(256) void k_a1(
    const unsigned* __restrict__ gcur, const unsigned* __restrict__ bbuf,
    const __half* __restrict__ xcath, __half* __restrict__ agg1h,
    int NSL, unsigned CAPS) {
  int tid = threadIdx.x;
  int lane = tid & 31;
  long grp = ((long)blockIdx.x * 256 + tid) >> 5;
  long ngrp = ((long)gridDim.x * 256) >> 5;
  __half2 one = __halves2half2(__float2half(1.0f), __float2half(0.0f));
  for (int bk = 0; bk < NSL; ++bk) {
    unsigned cnt = gcur[bk * 16]; if (cnt > CAPS) cnt = CAPS;
    const unsigned* bb = bbuf + (size_t)bk * CAPS;
    long sbase = (long)bk << SLICE_SHIFT;
    for (long i = grp; i < cnt; i += ngrp) {
      unsigned e = ntl_u32(bb + i);            // broadcast within group
      long dst = (long)(e & 0x1FFFFu);
      long src = sbase + (long)(e >> 17);
      if (lane < 10) {
        __half2 v = *(const __half2*)(xcath + src * 32 + lane * 2);  // L2-hot slice
        atomAddH2((__half2*)(agg1h + dst * 32 + lane * 2), v);
      } else if (lane == 10) {
        atomAddH2((__half2*)(agg1h + dst * 32 + 20), one);           // deg
      }
    }
  }
}

// ============ SAGE1: h1 = (agg1/deg)@W1l + b1l + x@W1r, + BN1 stats + rdeg ============
__global__ __launch_bounds__(256) void k_sage1(
    const __half* __restrict__ agg1h,
    const float* __restrict__ xs, const float* __restrict__ xt,
    const float* __restrict__ W1l, const float* __restrict__ b1l,
    const float* __restrict__ W1r,
    float* __restrict__ h1, float* __restrict__ rdeg_g,
    float* __restrict__ sum1, float* __restrict__ sq1, int N) {
  __shared__ float sWl[1280], sWr[1280];
  __shared__ float sm[4][21], sx[4][20];
  __shared__ float ls[256], lq[256];
  int tid = threadIdx.x;
  for (int i = tid; i < 1280; i += 256) { sWl[i] = W1l[i]; sWr[i] = W1r[i]; }
  int ln = tid >> 6, c = tid & 63;
  int n = blockIdx.x * 4 + ln;
  if (n < N && c < 21) sm[ln][c] = __half2float(agg1h[(long)n * 32 + c]);
  if (n < N && c < 20) sx[ln][c] = (c < 6) ? xs[(long)n * 6 + c] : xt[(long)n * 14 + c - 6];
  __syncthreads();
  float s_acc = 0.f, q_acc = 0.f;
  if (n < N) {
    float rd = 1.f / fmaxf(sm[ln][20], 1.f);
    if (c == 0) rdeg_g[n] = rd;
    float acc = b1l[c];
#pragma unroll
    for (int f = 0; f < 20; ++f)
      acc += (sm[ln][f] * rd) * sWl[f * 64 + c] + sx[ln][f] * sWr[f * 64 + c];
    h1[(long)n * 64 + c] = acc;
    s_acc = acc; q_acc = acc * acc;
  }
  ls[tid] = s_acc; lq[tid] = q_acc;
  __syncthreads();
  if (tid < 64) {
    float s = ls[tid], q = lq[tid];
#pragma unroll
    for (int r = 1; r < 4; ++r) { s += ls[tid + 64 * r]; q += lq[tid + 64 * r]; }
    atomicAdd(&sum1[tid], s);
    atomicAdd(&sq1[tid], q);
  }
}

// -------- BN1 + ReLU + p2lh = h@W2l (f16), p2r = h@W2r (in-place into h1) -------
__global__ __launch_bounds__(256) void k_bn1_proj(
    float* __restrict__ h1,
    const float* __restrict__ sum, const float* __restrict__ sq,
    const float* __restrict__ g, const float* __restrict__ be,
    const float* __restrict__ W2l, const float* __restrict__ W2r,
    __half* __restrict__ p2lh, int N) {
  __shared__ float sWl[64 * 32], sWr[64 * 32];
  __shared__ float sh[8][64];
  __shared__ float sscale[64], sshift[64];
  int tid = threadIdx.x;
  for (int i = tid; i < 2048; i += 256) { sWl[i] = W2l[i]; sWr[i] = W2r[i]; }
  if (tid < 64) {
    float m = sum[tid] / (float)N;
    float v = sq[tid] / (float)N - m * m;
    float inv = rsqrtf(v + BN_EPS);
    float sc = g[tid] * inv;
    sscale[tid] = sc;
    sshift[tid] = be[tid] - m * sc;
  }
  __syncthreads();
  long base = (long)blockIdx.x * 512;
#pragma unroll
  for (int k = 0; k < 2; ++k) {
    long j = base + tid + k * 256;
    if (j < (long)N * 64) {
      int c = (int)(j & 63);
      float v = h1[j] * sscale[c] + sshift[c];
      sh[(tid + k * 256) >> 6][c] = fmaxf(v, 0.f);
    }
  }
  __syncthreads();
  int c2 = tid & 31, ln = tid >> 5;
  int n = blockIdx.x * 8 + ln;
  if (n < N) {
    float al = 0.f, ar = 0.f;
#pragma unroll
    for (int c = 0; c < 64; ++c) {
      float hv = sh[ln][c];
      al += hv * sWl[c * 32 + c2];
      ar += hv * sWr[c * 32 + c2];
    }
    p2lh[(long)n * 32 + c2] = __float2half(al);
    h1[(long)n * 64 + c2] = ar;   // p2r in-place
  }
}

// ============ layer-2 agg: 32-lane group per edge, pk f16 atomics ============
__global__ __launch_bounds__(256) void k_a2(
    const unsigned* __restrict__ gcur, const unsigned* __restrict__ bbuf,
    const __half* __restrict__ p2lh, __half* __restrict__ agg2h,
    int NSL, unsigned CAPS) {
  int tid = threadIdx.x;
  int lane = tid & 31;
  long grp = ((long)blockIdx.x * 256 + tid) >> 5;
  long ngrp = ((long)gridDim.x * 256) >> 5;
  for (int bk = 0; bk < NSL; ++bk) {
    unsigned cnt = gcur[bk * 16]; if (cnt > CAPS) cnt = CAPS;
    const unsigned* bb = bbuf + (size_t)bk * CAPS;
    long sbase = (long)bk << SLICE_SHIFT;
    for (long i = grp; i < cnt; i += ngrp) {
      unsigned e = ntl_u32(bb + i);
      long dst = (long)(e & 0x1FFFFu);
      long src = sbase + (long)(e >> 17);
      if (lane < 16) {
        __half2 v = *(const __half2*)(p2lh + src * 32 + lane * 2);   // L2-hot slice
        atomAddH2((__half2*)(agg2h + dst * 32 + lane * 2), v);
      }
    }
  }
}

// ============ h2 = agg2*rdeg + b2l + p2r (in h1), + BN2 stats ============
__global__ __launch_bounds__(256) void k_h2s(
    const __half* __restrict__ agg2h, const float* __restrict__ b2l,
    const float* __restrict__ rdeg_g,
    float* __restrict__ h1,
    float* __restrict__ sum2, float* __restrict__ sq2, int N) {
  __shared__ float ls[256], lq[256];
  int tid = threadIdx.x;
  int c = tid & 31, ln = tid >> 5;
  int n = blockIdx.x * 8 + ln;
  float s_acc = 0.f, q_acc = 0.f;
  if (n < N) {
    long idx = (long)n * 64 + c;
    float h2 = __half2float(agg2h[(long)n * 32 + c]) * rdeg_g[n] + b2l[c] + h1[idx];
    h1[idx] = h2;
    s_acc = h2; q_acc = h2 * h2;
  }
  ls[tid] = s_acc; lq[tid] = q_acc;
  __syncthreads();
  if (tid < 32) {
    float s = ls[tid], q = lq[tid];
#pragma unroll
    for (int r = 1; r < 8; ++r) { s += ls[tid + 32 * r]; q += lq[tid + 32 * r]; }
    atomicAdd(&sum2[tid], s);
    atomicAdd(&sq2[tid], q);
  }
}

// ---------------- BN2 + ReLU + channel-mean + MLP head ----------------------
__global__ __launch_bounds__(256) void k_final(
    const float* __restrict__ h2,    // at [n*64+c], c<32
    const float* __restrict__ sum, const float* __restrict__ sq,
    const float* __restrict__ g, const float* __restrict__ be,
    const float* __restrict__ Wp, const float* __restrict__ bp,
    const float* __restrict__ Wo, const float* __restrict__ bo,
    float* __restrict__ out, int N) {
  int tid = threadIdx.x;
  int c = tid & 31, ln = tid >> 5;
  int n = blockIdx.x * 8 + ln;
  if (n >= N) return;
  float m = sum[c] / (float)N;
  float v = sq[c] / (float)N - m * m;
  float inv = rsqrtf(v + BN_EPS);
  float sc = g[c] * inv;
  float sh = be[c] - m * sc;
  float x = fmaxf(h2[(long)n * 64 + c] * sc + sh, 0.f);
#pragma unroll
  for (int msk = 16; msk >= 1; msk >>= 1) x += __shfl_xor(x, msk);
  float lr = x * (1.0f / 32.0f);
  float e = fmaxf(lr * Wp[c] + bp[c], 0.f) * Wo[c];
#pragma unroll
  for (int msk = 16; msk >= 1; msk >>= 1) e += __shfl_xor(e, msk);
  if (c == 0) out[n] = e + bo[0];
}

// ===================== fallback (round-0) atomic path =====================
__global__ __launch_bounds__(256) void k_edge_agg20(
    const int* __restrict__ srcA, const int* __restrict__ dstA,
    const float* __restrict__ xs, const float* __restrict__ xt,
    float* __restrict__ agg, float* __restrict__ deg, int E) {
  long gtid = (long)blockIdx.x * blockDim.x + threadIdx.x;
  int f = (int)(gtid & 31);
  long e = gtid >> 5;
  if (e >= E) return;
  int s = srcA[e], d = dstA[e];
  if (f < 20) {
    float v = (f < 6) ? xs[(long)s * 6 + f] : xt[(long)s * 14 + (f - 6)];
    atomicAdd(&agg[(long)d * 20 + f], v);
  }
  if (f == 0) atomicAdd(&deg[d], 1.0f);
}

__global__ __launch_bounds__(256) void k_sage1_fb(
    const float* __restrict__ agg, const float* __restrict__ deg,
    const float* __restrict__ xs, const float* __restrict__ xt,
    const float* __restrict__ W1l, const float* __restrict__ b1l,
    const float* __restrict__ W1r, float* __restrict__ h1, int N) {
  __shared__ float sWl[1280], sWr[1280];
  __shared__ float sm[4][20], sx[4][20];
  int tid = threadIdx.x;
  for (int i = tid; i < 1280; i += 256) { sWl[i] = W1l[i]; sWr[i] = W1r[i]; }
  int ln = tid >> 6, c = tid & 63;
  int n = blockIdx.x * 4 + ln;
  if (n < N && c < 20) {
    float dv = fmaxf(deg[n], 1.0f);
    sm[ln][c] = agg[(long)n * 20 + c] / dv;
    sx[ln][c] = (c < 6) ? xs[(long)n * 6 + c] : xt[(long)n * 14 + (c - 6)];
  }
  __syncthreads();
  if (n < N) {
    float acc = b1l[c];
#pragma unroll
    for (int f = 0; f < 20; ++f)
      acc += sm[ln][f] * sWl[f * 64 + c] + sx[ln][f] * sWr[f * 64 + c];
    h1[(long)n * 64 + c] = acc;
  }
}

__global__ __launch_bounds__(256) void k_stats(
    const float* __restrict__ h, int N, int C,
    float* __restrict__ sum, float* __restrict__ sq) {
  int tid = threadIdx.x;
  int rows = 256 / C;
  int c = tid % C, r = tid / C;
  float s = 0.f, q = 0.f;
  for (long n = (long)blockIdx.x * rows + r; n < N; n += (long)gridDim.x * rows) {
    float v = h[n * C + c];
    s += v; q += v * v;
  }
  __shared__ float ls[256], lq[256];
  ls[tid] = s; lq[tid] = q;
  __syncthreads();
  if (r == 0) {
    for (int rr = 1; rr < rows; ++rr) { s += ls[c + rr * C]; q += lq[c + rr * C]; }
    atomicAdd(&sum[c], s);
    atomicAdd(&sq[c], q);
  }
}

__global__ __launch_bounds__(256) void k_bn1_proj_fb(
    const float* __restrict__ h1,
    const float* __restrict__ sum, const float* __restrict__ sq,
    const float* __restrict__ g, const float* __restrict__ be,
    const float* __restrict__ W2l, const float* __restrict__ W2r,
    float* __restrict__ p2l, float* __restrict__ p2r, int N) {
  __shared__ float sWl[64 * 32], sWr[64 * 32];
  __shared__ float sh[8][64];
  __shared__ float sscale[64], sshift[64];
  int tid = threadIdx.x;
  for (int i = tid; i < 2048; i += 256) { sWl[i] = W2l[i]; sWr[i] = W2r[i]; }
  if (tid < 64) {
    float m = sum[tid] / (float)N;
    float v = sq[tid] / (float)N - m * m;
    float inv = rsqrtf(v + BN_EPS);
    float sc = g[tid] * inv;
    sscale[tid] = sc;
    sshift[tid] = be[tid] - m * sc;
  }
  __syncthreads();
  long base = (long)blockIdx.x * 512;
#pragma unroll
  for (int k = 0; k < 2; ++k) {
    long j = base + tid + k * 256;
    if (j < (long)N * 64) {
      int c = (int)(j & 63);
      float v = h1[j] * sscale[c] + sshift[c];
      sh[(tid + k * 256) >> 6][c] = fmaxf(v, 0.f);
    }
  }
  __syncthreads();
  int c2 = tid & 31, ln = tid >> 5;
  int n = blockIdx.x * 8 + ln;
  if (n < N) {
    float al = 0.f, ar = 0.f;
#pragma unroll
    for (int c = 0; c < 64; ++c) {
      float hv = sh[ln][c];
      al += hv * sWl[c * 32 + c2];
      ar += hv * sWr[c * 32 + c2];
    }
    p2l[(long)n * 32 + c2] = al;
    p2r[(long)n * 32 + c2] = ar;
  }
}

__global__ __launch_bounds__(256) void k_edge_agg32(
    const int* __restrict__ srcA, const int* __restrict__ dstA,
    const float* __restrict__ p, float* __restrict__ agg, int E) {
  long gtid = (long)blockIdx.x * blockDim.x + threadIdx.x;
  int f = (int)(gtid & 31);
  long e = gtid >> 5;
  if (e >= E) return;
  atomicAdd(&agg[(long)dstA[e] * 32 + f], p[(long)srcA[e] * 32 + f]);
}

__global__ __launch_bounds__(256) void k_h2_fb(
    const float* __restrict__ agg, const float* __restrict__ deg,
    const float* __restrict__ b2l, const float* __restrict__ p2r,
    float* __restrict__ h2, int N) {
  long i = (long)blockIdx.x * blockDim.x + threadIdx.x;
  if (i >= (long)N * 32) return;
  int n = (int)(i >> 5), f = (int)(i & 31);
  float dv = fmaxf(deg[n], 1.0f);
  h2[i] = agg[i] / dv + b2l[f] + p2r[i];
}

__global__ __launch_bounds__(256) void k_final_fb(
    const float* __restrict__ h2,
    const float* __restrict__ sum, const float* __restrict__ sq,
    const float* __restrict__ g, const float* __restrict__ be,
    const float* __restrict__ Wp, const float* __restrict__ bp,
    const float* __restrict__ Wo, const float* __restrict__ bo,
    float* __restrict__ out, int N) {
  int tid = threadIdx.x;
  int c = tid & 31, ln = tid >> 5;
  int n = blockIdx.x * 8 + ln;
  if (n >= N) return;
  float m = sum[c] / (float)N;
  float v = sq[c] / (float)N - m * m;
  float inv = rsqrtf(v + BN_EPS);
  float sc = g[c] * inv;
  float sh = be[c] - m * sc;
  float x = fmaxf(h2[(long)n * 32 + c] * sc + sh, 0.f);
#pragma unroll
  for (int msk = 16; msk >= 1; msk >>= 1) x += __shfl_xor(x, msk);
  float lr = x * (1.0f / 32.0f);
  float e = fmaxf(lr * Wp[c] + bp[c], 0.f) * Wo[c];
#pragma unroll
  for (int msk = 16; msk >= 1; msk >>= 1) e += __shfl_xor(e, msk);
  if (c == 0) out[n] = e + bo[0];
}

extern "C" void kernel_launch(void* const* d_in, const int* in_sizes, int n_in,
                              void* d_out, int out_size, void* d_ws, size_t ws_size,
                              hipStream_t stream) {
  const float* xs  = (const float*)d_in[0];
  const float* xt  = (const float*)d_in[1];
  const int*   ei  = (const int*)d_in[2];
  const float* W1l = (const float*)d_in[3];
  const float* b1l = (const float*)d_in[4];
  const float* W1r = (const float*)d_in[5];
  const float* g1  = (const float*)d_in[6];
  const float* be1 = (const float*)d_in[7];
  const float* W2l = (const float*)d_in[8];
  const float* b2l = (const float*)d_in[9];
  const float* W2r = (const float*)d_in[10];
  const float* g2  = (const float*)d_in[11];
  const float* be2 = (const float*)d_in[12];
  const float* Wp  = (const float*)d_in[13];
  const float* bp  = (const float*)d_in[14];
  const float* Wo  = (const float*)d_in[15];
  const float* bo  = (const float*)d_in[16];
  float* out = (float*)d_out;

  int N = in_sizes[0] / 6;
  int E = in_sizes[2] / 2;
  const int* srcA = ei;
  const int* dstA = ei + E;
  const int tb = 256;

  int NSL = (N + SLICE - 1) >> SLICE_SHIFT;
  unsigned CAPS = (unsigned)(((long)E << SLICE_SHIFT) / (N > 0 ? N : 1));
  CAPS += CAPS / 16 + 1024;
  CAPS = (CAPS + 3u) & ~3u;

  // ws layout (u32 units):
  // gcur[256] | stats[192] | aggH f16[16N u32] (agg1h, reused as agg2h) |
  // xcath f16[16N] | p2lh f16[16N] | bbuf[NSL*CAPS] | h1[64N] | rdeg[N]
  size_t nu = (size_t)N;
  size_t off_gcur  = 0;
  size_t off_stats = 256;
  size_t off_aggH  = 448;
  size_t off_xcat  = off_aggH + 16 * nu;
  size_t off_p2l   = off_xcat + 16 * nu;
  size_t off_bbuf  = off_p2l + 16 * nu;
  size_t off_h1    = off_bbuf + (size_t)NSL * CAPS;
  size_t off_rdeg  = off_h1 + 64 * nu;
  size_t needB     = (off_rdeg + nu) * 4;

  if (ws_size >= needB && N <= 131072 && NSL <= 16) {
    unsigned* base32 = (unsigned*)d_ws;
    unsigned* gcur  = base32 + off_gcur;
    float*    stats = (float*)(base32 + off_stats);
    float* sum1 = stats, * sq1 = stats + 64, * sum2 = stats + 128, * sq2 = stats + 160;
    __half*   aggH  = (__half*)(base32 + off_aggH);
    __half*   xcath = (__half*)(base32 + off_xcat);
    __half*   p2lh  = (__half*)(base32 + off_p2l);
    unsigned* bbuf  = base32 + off_bbuf;
    float*    h1    = (float*)(base32 + off_h1);
    float*    rdeg  = (float*)(base32 + off_rdeg);

    // zero gcur + stats + agg1h (contiguous prefix)
    hipMemsetAsync(base32, 0, (off_aggH + 16 * nu) * 4, stream);

    k_xcat<<<(int)(((long)N * 32 + tb - 1) / tb), tb, 0, stream>>>(xs, xt, xcath, N);
    k_sc<<<1024, tb, 0, stream>>>(srcA, dstA, gcur, bbuf, E, CAPS);
    k_a1<<<1024, tb, 0, stream>>>(gcur, bbuf, xcath, aggH, NSL, CAPS);
    k_sage1<<<(N + 3) / 4, tb, 0, stream>>>(aggH, xs, xt, W1l, b1l, W1r,
                                            h1, rdeg, sum1, sq1, N);
    hipMemsetAsync(aggH, 0, 16 * nu * 4, stream);   // agg2h overlay
    k_bn1_proj<<<(N + 7) / 8, tb, 0, stream>>>(h1, sum1, sq1, g1, be1, W2l, W2r, p2lh, N);
    k_a2<<<1024, tb, 0, stream>>>(gcur, bbuf, p2lh, aggH, NSL, CAPS);
    k_h2s<<<(N + 7) / 8, tb, 0, stream>>>(aggH, b2l, rdeg, h1, sum2, sq2, N);
    k_final<<<(N + 7) / 8, tb, 0, stream>>>(h1, sum2, sq2, g2, be2, Wp, bp, Wo, bo, out, N);
  } else {
    // ---- fallback: round-0 atomic path ----
    float* ws   = (float*)d_ws;
    float* deg  = ws;
    float* agg1 = deg + N;
    float* h1   = agg1 + (long)20 * N;
    float* agg2 = h1;
    float* h2   = h1 + (long)32 * N;
    float* p2l  = h1 + (long)64 * N;
    float* p2r  = p2l + (long)32 * N;
    float* stats = p2r + (long)32 * N;
    float* sum1 = stats, * sq1 = stats + 64, * sum2 = stats + 128, * sq2 = stats + 160;

    hipMemsetAsync(deg, 0, sizeof(float) * (size_t)(21 * (long)N), stream);
    hipMemsetAsync(stats, 0, sizeof(float) * 192, stream);

    long t1 = (long)E * 32;
    int eblocks = (int)((t1 + tb - 1) / tb);
    k_edge_agg20<<<eblocks, tb, 0, stream>>>(srcA, dstA, xs, xt, agg1, deg, E);
    k_sage1_fb<<<(N + 3) / 4, tb, 0, stream>>>(agg1, deg, xs, xt, W1l, b1l, W1r, h1, N);
    k_stats<<<1024, tb, 0, stream>>>(h1, N, 64, sum1, sq1);
    k_bn1_proj_fb<<<(N + 7) / 8, tb, 0, stream>>>(h1, sum1, sq1, g1, be1, W2l, W2r, p2l, p2r, N);
    hipMemsetAsync(agg2, 0, sizeof(float) * (size_t)(32 * (long)N), stream);
    k_edge_agg32<<<eblocks, tb, 0, stream>>>(srcA, dstA, p2l, agg2, E);
    k_h2_fb<<<(int)(((long)32 * N + tb - 1) / tb), tb, 0, stream>>>(agg2, deg, b2l, p2r, h2, N);
    k_stats<<<1024, tb, 0, stream>>>(h2, N, 32, sum2, sq2);
    k_final_fb<<<(N + 7) / 8, tb, 0, stream>>>(h2, sum2, sq2, g2, be2, Wp, bp, Wo, bo, out, N);
  }
}